// Round 6
// baseline (205.819 us; speedup 1.0000x reference)
//
#include <hip/hip_runtime.h>
#include <stdint.h>

// N=16384 points, K=10 (fixed by setup_inputs).
#define NPTS   16384
#define TOPK   10
#define NBX    32                 // 32x32x32 cells over [-5,5]^3
#define NBK    (32 * 32 * 32)
#define XMIN   (-5.0f)
#define INVBW  (3.2f)             // 32 / 10.0
#define CELLW  (0.3125f)
#define SENT_STEP 0x4000u         // one ulp at masked-key granularity (= idx field)
#define LIGHT_MAX 512u            // candidate cap for the 16-lane path
#define HEAVY_GRID 1024           // x4 waves = 4096 concurrent heavy points

// ws layout (bytes):
//   0       accum[4] floats (sparsity, scale, opacity, smooth)
//   16      qcnt (uint)            heavy-queue counter
//   20      done (uint)            heavy-block completion counter
//   256     hist[NBK] uint  -> re-zeroed by prefix_scan, reused as cnt,
//                              then DEAD after scatter -> reused as queue[]
//   131328  base[NBK+1] uint
//   262464  r2m[NPTS] uint        (stepped sentinel, written for heavy pts only)
//   328064  sorted[NPTS] float4   (x,y,z,opacity) ordered by (bx,by,bz)
// memset zeroes [0, 131328).

__device__ __forceinline__ unsigned umin_(unsigned a, unsigned b) { return a < b ? a : b; }
__device__ __forceinline__ unsigned umax_(unsigned a, unsigned b) { return a > b ? a : b; }

// Branchless ascending insert (19 independent min/max).
__device__ __forceinline__ void chain_insert(unsigned a[TOPK], unsigned key) {
#pragma unroll
    for (int k = TOPK - 1; k > 0; --k) a[k] = umin_(umax_(a[k - 1], key), a[k]);
    a[0] = umin_(a[0], key);
}

__device__ __forceinline__ void ce_(unsigned &x, unsigned &y) {
    unsigned lo = umin_(x, y); y = umax_(x, y); x = lo;
}

// Bitonic merge network for a length-10 bitonic sequence (15 CEs).
__device__ __forceinline__ void bitonic10(unsigned a[TOPK]) {
    ce_(a[0], a[8]); ce_(a[1], a[9]);
    ce_(a[0], a[4]); ce_(a[1], a[5]); ce_(a[2], a[6]); ce_(a[3], a[7]);
    ce_(a[0], a[2]); ce_(a[1], a[3]); ce_(a[4], a[6]); ce_(a[5], a[7]);
    ce_(a[0], a[1]); ce_(a[2], a[3]); ce_(a[4], a[5]); ce_(a[6], a[7]); ce_(a[8], a[9]);
}

// Merge two sorted 10-lists: ours + partner lane's (halver + bitonic net).
__device__ __forceinline__ void merge_shfl(unsigned a[TOPK], int w) {
    unsigned b[TOPK];
#pragma unroll
    for (int k = 0; k < TOPK; ++k) b[k] = (unsigned)__shfl_xor((int)a[k], w, 64);
#pragma unroll
    for (int k = 0; k < TOPK; ++k) a[k] = umin_(a[k], b[TOPK - 1 - k]);
    bitonic10(a);
}

// Process two candidates with both loads issued before either use.
__device__ __forceinline__ void scan2(
    unsigned a[TOPK], const float4* __restrict__ sorted,
    unsigned p0, unsigned p1, unsigned s, float mx, float my, float mz)
{
    float4 c0 = sorted[p0];
    float4 c1 = sorted[p1];
    float dx0 = c0.x - mx, dy0 = c0.y - my, dz0 = c0.z - mz;
    float dx1 = c1.x - mx, dy1 = c1.y - my, dz1 = c1.z - mz;
    float d20 = fmaf(dx0, dx0, fmaf(dy0, dy0, dz0 * dz0));
    float d21 = fmaf(dx1, dx1, fmaf(dy1, dy1, dz1 * dz1));
    unsigned k0 = (__float_as_uint(d20) & 0xFFFFC000u) | p0;
    unsigned k1 = (__float_as_uint(d21) & 0xFFFFC000u) | p1;
    if (p0 == s) k0 = 0xFFFFFFFFu;
    if (p1 == s) k1 = 0xFFFFFFFFu;
    unsigned kmin = umin_(k0, k1), kmax = umax_(k0, k1);
    if (kmin < a[TOPK - 1]) {
        chain_insert(a, kmin);
        if (kmax < a[TOPK - 1]) chain_insert(a, kmax);
    }
}

__device__ __forceinline__ void scan1(
    unsigned a[TOPK], const float4* __restrict__ sorted,
    unsigned p, unsigned s, float mx, float my, float mz)
{
    float4 c = sorted[p];
    float dx = c.x - mx, dy = c.y - my, dz = c.z - mz;
    float d2 = fmaf(dx, dx, fmaf(dy, dy, dz * dz));
    unsigned key = (__float_as_uint(d2) & 0xFFFFC000u) | p;
    if (p == s) key = 0xFFFFFFFFu;
    if (key < a[TOPK - 1]) chain_insert(a, key);
}

__device__ __forceinline__ int cellf(float v) {
    int b = (int)((v - XMIN) * INVBW);
    return min(max(b, 0), NBX - 1);
}

// ---- fused trivial losses + 3-D cell histogram ----------------------------
__global__ __launch_bounds__(256) void setup_kernel(
    const float* __restrict__ pos, const float* __restrict__ opac,
    const float* __restrict__ scales, float* __restrict__ accum,
    unsigned* __restrict__ hist)
{
    int i = blockIdx.x * 256 + threadIdx.x;
    float o = opac[i];
    float d = o - 0.5f;
    float s_sp = fabsf(o);
    float s_op = d * d;
    float s_sc = fabsf(scales[3 * i] - 1.0f) + fabsf(scales[3 * i + 1] - 1.0f)
               + fabsf(scales[3 * i + 2] - 1.0f);
    int bx = cellf(pos[3 * i]);
    int by = cellf(pos[3 * i + 1]);
    int bz = cellf(pos[3 * i + 2]);
    atomicAdd(&hist[(bx << 10) | (by << 5) | bz], 1u);
#pragma unroll
    for (int off = 32; off > 0; off >>= 1) {
        s_sp += __shfl_down(s_sp, off, 64);
        s_sc += __shfl_down(s_sc, off, 64);
        s_op += __shfl_down(s_op, off, 64);
    }
    if ((threadIdx.x & 63) == 0) {
        atomicAdd(&accum[0], s_sp);
        atomicAdd(&accum[1], s_sc);
        atomicAdd(&accum[2], s_op);
    }
}

// Exclusive scan over 32768 bins: shfl-based (2 barriers total).
// Also re-zeroes hist in place (it becomes the scatter cnt array).
__global__ __launch_bounds__(1024) void prefix_scan(
    unsigned* __restrict__ hist, unsigned* __restrict__ base)
{
    __shared__ unsigned wsum[16];
    const int t = threadIdx.x;
    const int lane = t & 63, wid = t >> 6;
    unsigned loc[32];
    uint4* h4 = (uint4*)(hist + t * 32);
#pragma unroll
    for (int j = 0; j < 8; ++j) {
        uint4 h = h4[j];
        loc[4 * j + 0] = h.x; loc[4 * j + 1] = h.y;
        loc[4 * j + 2] = h.z; loc[4 * j + 3] = h.w;
    }
    unsigned run = 0;
#pragma unroll
    for (int j = 0; j < 32; ++j) { unsigned v = loc[j]; loc[j] = run; run += v; }
    unsigned inc = run;
#pragma unroll
    for (int off = 1; off < 64; off <<= 1) {
        unsigned v = (unsigned)__shfl_up((int)inc, off, 64);
        if (lane >= off) inc += v;
    }
    if (lane == 63) wsum[wid] = inc;
    __syncthreads();
    if (wid == 0) {
        unsigned w = (lane < 16) ? wsum[lane] : 0u;
#pragma unroll
        for (int off = 1; off < 16; off <<= 1) {
            unsigned v = (unsigned)__shfl_up((int)w, off, 64);
            if (lane >= off) w += v;
        }
        if (lane < 16) wsum[lane] = w;
    }
    __syncthreads();
    const unsigned wbase = (wid > 0) ? wsum[wid - 1] : 0u;
    const unsigned tbase = wbase + inc - run;
    uint4* b4 = (uint4*)(base + t * 32);
#pragma unroll
    for (int j = 0; j < 8; ++j) {
        b4[j] = make_uint4(loc[4 * j] + tbase, loc[4 * j + 1] + tbase,
                           loc[4 * j + 2] + tbase, loc[4 * j + 3] + tbase);
        h4[j] = make_uint4(0u, 0u, 0u, 0u);
    }
    if (t == 1023) base[NBK] = NPTS;
}

__global__ __launch_bounds__(256) void scatter_sorted(
    const float* __restrict__ pos, const float* __restrict__ opac,
    const unsigned* __restrict__ base, unsigned* __restrict__ cnt,
    float4* __restrict__ sorted)
{
    int i = blockIdx.x * 256 + threadIdx.x;
    float x = pos[3 * i], y = pos[3 * i + 1], z = pos[3 * i + 2];
    int b = (cellf(x) << 10) | (cellf(y) << 5) | cellf(z);
    unsigned p = base[b] + atomicAdd(&cnt[b], 1u);
    sorted[p] = make_float4(x, y, z, opac[i]);
}

// ---- fused kNN: bound pass + windowed exact scan + smoothness -------------
// 16 lanes/point (4 points/wave). All 4096 waves co-resident; runtime =
// slowest wave. Light path capped at LIGHT_MAX candidates (~32/lane worst).
__global__ __launch_bounds__(256) void knn_main(
    const float4* __restrict__ sorted, const unsigned* __restrict__ base,
    unsigned* __restrict__ r2m, unsigned* __restrict__ qcnt,
    int* __restrict__ queue, float* __restrict__ accum)
{
    __shared__ float ssum;
    if (threadIdx.x == 0) ssum = 0.0f;
    __syncthreads();

    const int sub = threadIdx.x & 15;
    const int s   = blockIdx.x * 16 + (threadIdx.x >> 4);

    const float4 me = sorted[s];

    // ---- phase A: bound from the +/-128 cell-order window ----
    unsigned a[TOPK];
#pragma unroll
    for (int k = 0; k < TOPK; ++k) a[k] = 0xFFFFFFFFu;
    {
        const int dir = sub >> 3;               // 0 right, 1 left
        const int start = 1 + (sub & 7) * 16;
#pragma unroll 4
        for (int t = 0; t < 16; ++t) {
            int p = dir ? (s - start - t) : (s + start + t);
            int pc = min(max(p, 0), NPTS - 1);
            float4 c = sorted[pc];
            float dx = c.x - me.x, dy = c.y - me.y, dz = c.z - me.z;
            float d2 = fmaf(dx, dx, fmaf(dy, dy, dz * dz));
            unsigned key = (__float_as_uint(d2) & 0xFFFFC000u) | (unsigned)pc;
            if (p < 0 || p >= NPTS) key = 0xFFFFFFFFu;
            chain_insert(a, key);
        }
    }
    merge_shfl(a, 1); merge_shfl(a, 2); merge_shfl(a, 4); merge_shfl(a, 8);
    const unsigned sentinel = (a[TOPK - 1] & 0xFFFFC000u) + SENT_STEP;
    const float R = sqrtf(__uint_as_float(sentinel)) + 1e-6f;

    const int bxlo = cellf(me.x - R), bxhi = cellf(me.x + R);
    const int bylo = cellf(me.y - R), byhi = cellf(me.y + R);
    const int bzlo = cellf(me.z - R), bzhi = cellf(me.z + R);
    const int nyw   = byhi - bylo + 1;
    const int npair = (bxhi - bxlo + 1) * nyw;

    // per-lane pair iterator constants (division once, then div-free stepping)
    const int q0  = sub / nyw, r0  = sub - q0 * nyw;
    const int q16 = 16 / nyw,  r16 = 16 - q16 * nyw;

    // ---- phase B: classify (lanes strided over column pairs) ----
    unsigned csum = 0;
    {
        int bx = bxlo + q0, byo = r0;
        for (int pi = sub; pi < npair; pi += 16) {
            int cb = (bx << 10) | ((bylo + byo) << 5);
            csum += base[cb + bzhi + 1] - base[cb + bzlo];
            byo += r16; bx += q16;
            if (byo >= nyw) { byo -= nyw; ++bx; }
        }
    }
#pragma unroll
    for (int off = 1; off <= 8; off <<= 1)
        csum += (unsigned)__shfl_xor((int)csum, off, 64);
    const bool heavy = csum > LIGHT_MAX;
    if (heavy && sub == 0) {
        r2m[s] = sentinel;                       // pass sentinel to heavy path
        unsigned q = atomicAdd(qcnt, 1u);
        queue[q] = s;
    }

    // ---- phase C: per-lane-parallel scan, next-pair bounds prefetched ----
#pragma unroll
    for (int k = 0; k < TOPK; ++k) a[k] = sentinel;
    if (!heavy) {
        int bx = bxlo + q0, byo = r0;
        int pi = sub;
        unsigned lo = 0, hi = 0;
        if (pi < npair) {
            int cb = (bx << 10) | ((bylo + byo) << 5);
            lo = base[cb + bzlo]; hi = base[cb + bzhi + 1];
        }
        while (pi < npair) {
            const int npi = pi + 16;
            byo += r16; bx += q16;
            if (byo >= nyw) { byo -= nyw; ++bx; }
            unsigned nlo = 0, nhi = 0;
            if (npi < npair) {                   // prefetch next pair's bounds
                int cb = (bx << 10) | ((bylo + byo) << 5);
                nlo = base[cb + bzlo]; nhi = base[cb + bzhi + 1];
            }
            unsigned p = lo;
            for (; p + 1 < hi; p += 2)
                scan2(a, sorted, p, p + 1, (unsigned)s, me.x, me.y, me.z);
            if (p < hi)
                scan1(a, sorted, p, (unsigned)s, me.x, me.y, me.z);
            pi = npi; lo = nlo; hi = nhi;
        }
        merge_shfl(a, 1); merge_shfl(a, 2); merge_shfl(a, 4); merge_shfl(a, 8);
    }

    float v = 0.0f;
    if (!heavy && sub < TOPK) {
        int j = (int)(a[sub] & 0x3FFFu);
        v = fabsf(me.w - sorted[j].w);
    }
    v += __shfl_down(v, 8, 64);
    v += __shfl_down(v, 4, 64);
    v += __shfl_down(v, 2, 64);
    v += __shfl_down(v, 1, 64);
    if (sub == 0) atomicAdd(&ssum, v);
    __syncthreads();
    if (threadIdx.x == 0) atomicAdd(&accum[3], ssum);
}

// ---- heavy path + final combine -------------------------------------------
// ONE WAVE per queued point (4096 wave slots -> all heavy points concurrent).
// No barriers in the per-point loop: wave-local box-expansion bound (smallest
// m with >= 11 points in [b +/- m]^3 gives r10 <= sqrt(3)*(m+1)*w), 64-lane
// pair-parallel scan (2 loads in flight), 6-level shfl merge. Last block
// computes the final output.
__global__ __launch_bounds__(256) void knn_heavy(
    const float4* __restrict__ sorted, const unsigned* __restrict__ r2m,
    const unsigned* __restrict__ base, const unsigned* __restrict__ qcnt,
    const int* __restrict__ queue, float* __restrict__ accum,
    unsigned* __restrict__ done, float* __restrict__ out)
{
    const int lane = threadIdx.x & 63;
    const int wave = (blockIdx.x * 256 + threadIdx.x) >> 6;
    const int nq   = (int)*qcnt;

    for (int qi = wave; qi < nq; qi += HEAVY_GRID * 4) {
        const int s = queue[qi];
        const float4 me = sorted[s];
        const unsigned sent1 = r2m[s];           // already stepped

        // wave-local box expansion (shfl-only, no barriers)
        unsigned sentinel = sent1;
        {
            const int bx = cellf(me.x), by = cellf(me.y), bz = cellf(me.z);
            for (int m = 1; m < 32; ++m) {
                const int xlo = max(bx - m, 0), xhi = min(bx + m, NBX - 1);
                const int ylo = max(by - m, 0), yhi = min(by + m, NBX - 1);
                const int zlo = max(bz - m, 0), zhi = min(bz + m, NBX - 1);
                const int ny = yhi - ylo + 1;
                const int np = (xhi - xlo + 1) * ny;
                unsigned c = 0;
                for (int pi = lane; pi < np; pi += 64) {
                    int cbx = xlo + pi / ny, cby = ylo + pi % ny;
                    int cb = (cbx << 10) | (cby << 5);
                    c += base[cb + zhi + 1] - base[cb + zlo];
                }
#pragma unroll
                for (int off = 32; off > 0; off >>= 1)
                    c += (unsigned)__shfl_xor((int)c, off, 64);
                if (c >= 11u) {
                    float Rb = CELLW * 1.7320508f * (float)(m + 1);
                    unsigned sb = (__float_as_uint(Rb * Rb) & 0xFFFFC000u) + SENT_STEP;
                    sentinel = umin_(sent1, sb);
                    break;
                }
            }
        }
        const float R = sqrtf(__uint_as_float(sentinel)) + 1e-6f;

        const int bxlo = cellf(me.x - R), bxhi = cellf(me.x + R);
        const int bylo = cellf(me.y - R), byhi = cellf(me.y + R);
        const int bzlo = cellf(me.z - R), bzhi = cellf(me.z + R);
        const int nyw   = byhi - bylo + 1;
        const int npair = (bxhi - bxlo + 1) * nyw;

        unsigned a[TOPK];
#pragma unroll
        for (int k = 0; k < TOPK; ++k) a[k] = sentinel;

        for (int pi = lane; pi < npair; pi += 64) {
            int cbx = bxlo + pi / nyw, cby = bylo + pi % nyw;
            int cb = (cbx << 10) | (cby << 5);
            unsigned lo = base[cb + bzlo], hi = base[cb + bzhi + 1];
            unsigned p = lo;
            for (; p + 1 < hi; p += 2)
                scan2(a, sorted, p, p + 1, (unsigned)s, me.x, me.y, me.z);
            if (p < hi)
                scan1(a, sorted, p, (unsigned)s, me.x, me.y, me.z);
        }

        merge_shfl(a, 1);  merge_shfl(a, 2);  merge_shfl(a, 4);
        merge_shfl(a, 8);  merge_shfl(a, 16); merge_shfl(a, 32);

        float v = 0.0f;
        if (lane < TOPK) {
            int j = (int)(a[lane] & 0x3FFFu);
            v = fabsf(me.w - sorted[j].w);
        }
        v += __shfl_down(v, 8, 64);
        v += __shfl_down(v, 4, 64);
        v += __shfl_down(v, 2, 64);
        v += __shfl_down(v, 1, 64);
        if (lane == 0) atomicAdd(&accum[3], v);
    }

    // last block to arrive computes the final output (replaces combine kernel)
    __syncthreads();
    __threadfence();
    if (threadIdx.x == 0) {
        unsigned d = atomicAdd(done, 1u);
        if (d == HEAVY_GRID - 1) {
            float sp = atomicAdd(&accum[0], 0.0f);
            float sc = atomicAdd(&accum[1], 0.0f);
            float op = atomicAdd(&accum[2], 0.0f);
            float sm = atomicAdd(&accum[3], 0.0f);
            const float n = (float)NPTS;
            out[0] = 0.01f * (sp / n) + 0.1f * (sm / (n * 10.0f))
                   + sc / (3.0f * n) + op / n;
        }
    }
}

extern "C" void kernel_launch(void* const* d_in, const int* in_sizes, int n_in,
                              void* d_out, int out_size, void* d_ws, size_t ws_size,
                              hipStream_t stream)
{
    const float* pos    = (const float*)d_in[0];
    const float* opac   = (const float*)d_in[1];
    const float* scales = (const float*)d_in[2];
    float* out = (float*)d_out;

    char* ws = (char*)d_ws;
    float*    accum  = (float*)ws;
    unsigned* qcnt   = (unsigned*)(ws + 16);
    unsigned* done   = (unsigned*)(ws + 20);
    unsigned* histcnt= (unsigned*)(ws + 256);      // hist -> cnt -> queue
    int*      queue  = (int*)(ws + 256);
    unsigned* base   = (unsigned*)(ws + 131328);
    unsigned* r2m    = (unsigned*)(ws + 262464);
    float4*   sorted = (float4*)(ws + 328064);

    hipMemsetAsync(ws, 0, 131328, stream);

    setup_kernel  <<<NPTS / 256, 256, 0, stream>>>(pos, opac, scales, accum, histcnt);
    prefix_scan   <<<1, 1024, 0, stream>>>(histcnt, base);
    scatter_sorted<<<NPTS / 256, 256, 0, stream>>>(pos, opac, base, histcnt, sorted);
    knn_main      <<<NPTS * 16 / 256, 256, 0, stream>>>(sorted, base, r2m, qcnt, queue, accum);
    knn_heavy     <<<HEAVY_GRID, 256, 0, stream>>>(sorted, r2m, base, qcnt, queue, accum, done, out);
}

// Round 7
// 144.865 us; speedup vs baseline: 1.4208x; 1.4208x over previous
//
#include <hip/hip_runtime.h>
#include <stdint.h>

// N=16384 points, K=10 (fixed by setup_inputs).
#define NPTS   16384
#define TOPK   10
#define NBX    32                 // 32x32x32 cells over [-5,5]^3
#define NBK    (32 * 32 * 32)
#define XMIN   (-5.0f)
#define INVBW  (3.2f)             // 32 / 10.0
#define SENT_STEP 0x4000u         // one ulp at masked-key granularity (= idx field)
#define LIGHT_MAX 512u            // candidate cap for the 16-lane path
#define HEAVY_GRID 1024           // x4 waves = 4096 concurrent heavy points
#define NSLOT  64                 // padded accumulator slots (128 B apart)

// ws layout (bytes):
//   0       accum[4] floats (sparsity, scale, opacity, -)
//   16      qcnt (uint)
//   128     parts[NSLOT] floats, stride 32 floats = 128 B   [128, 8320)
//   8448    hist[NBK] uint -> cnt -> queue                  [8448, 139520)
//   139520  base[NBK+1] uint                                [139520, 270596)
//   270720  r2m[NPTS] uint   (stepped sentinel, heavy pts)  [270720, 336256)
//   336256  sorted[NPTS] float4 (x,y,z,opacity) cell-order  [336256, 598400)
// memset zeroes [0, 139520).

__device__ __forceinline__ unsigned umin_(unsigned a, unsigned b) { return a < b ? a : b; }
__device__ __forceinline__ unsigned umax_(unsigned a, unsigned b) { return a > b ? a : b; }

// Branchless ascending insert (19 independent min/max).
__device__ __forceinline__ void chain_insert(unsigned a[TOPK], unsigned key) {
#pragma unroll
    for (int k = TOPK - 1; k > 0; --k) a[k] = umin_(umax_(a[k - 1], key), a[k]);
    a[0] = umin_(a[0], key);
}

__device__ __forceinline__ void ce_(unsigned &x, unsigned &y) {
    unsigned lo = umin_(x, y); y = umax_(x, y); x = lo;
}

// Bitonic merge network for a length-10 bitonic sequence (15 CEs).
__device__ __forceinline__ void bitonic10(unsigned a[TOPK]) {
    ce_(a[0], a[8]); ce_(a[1], a[9]);
    ce_(a[0], a[4]); ce_(a[1], a[5]); ce_(a[2], a[6]); ce_(a[3], a[7]);
    ce_(a[0], a[2]); ce_(a[1], a[3]); ce_(a[4], a[6]); ce_(a[5], a[7]);
    ce_(a[0], a[1]); ce_(a[2], a[3]); ce_(a[4], a[5]); ce_(a[6], a[7]); ce_(a[8], a[9]);
}

// Merge two sorted 10-lists: ours + partner lane's (halver + bitonic net).
__device__ __forceinline__ void merge_shfl(unsigned a[TOPK], int w) {
    unsigned b[TOPK];
#pragma unroll
    for (int k = 0; k < TOPK; ++k) b[k] = (unsigned)__shfl_xor((int)a[k], w, 64);
#pragma unroll
    for (int k = 0; k < TOPK; ++k) a[k] = umin_(a[k], b[TOPK - 1 - k]);
    bitonic10(a);
}

// Process two candidates with both loads issued before either use.
__device__ __forceinline__ void scan2(
    unsigned a[TOPK], const float4* __restrict__ sorted,
    unsigned p0, unsigned p1, unsigned s, float mx, float my, float mz)
{
    float4 c0 = sorted[p0];
    float4 c1 = sorted[p1];
    float dx0 = c0.x - mx, dy0 = c0.y - my, dz0 = c0.z - mz;
    float dx1 = c1.x - mx, dy1 = c1.y - my, dz1 = c1.z - mz;
    float d20 = fmaf(dx0, dx0, fmaf(dy0, dy0, dz0 * dz0));
    float d21 = fmaf(dx1, dx1, fmaf(dy1, dy1, dz1 * dz1));
    unsigned k0 = (__float_as_uint(d20) & 0xFFFFC000u) | p0;
    unsigned k1 = (__float_as_uint(d21) & 0xFFFFC000u) | p1;
    if (p0 == s) k0 = 0xFFFFFFFFu;
    if (p1 == s) k1 = 0xFFFFFFFFu;
    unsigned kmin = umin_(k0, k1), kmax = umax_(k0, k1);
    if (kmin < a[TOPK - 1]) {
        chain_insert(a, kmin);
        if (kmax < a[TOPK - 1]) chain_insert(a, kmax);
    }
}

__device__ __forceinline__ void scan1(
    unsigned a[TOPK], const float4* __restrict__ sorted,
    unsigned p, unsigned s, float mx, float my, float mz)
{
    float4 c = sorted[p];
    float dx = c.x - mx, dy = c.y - my, dz = c.z - mz;
    float d2 = fmaf(dx, dx, fmaf(dy, dy, dz * dz));
    unsigned key = (__float_as_uint(d2) & 0xFFFFC000u) | p;
    if (p == s) key = 0xFFFFFFFFu;
    if (key < a[TOPK - 1]) chain_insert(a, key);
}

__device__ __forceinline__ int cellf(float v) {
    int b = (int)((v - XMIN) * INVBW);
    return min(max(b, 0), NBX - 1);
}

// ---- fused trivial losses + 3-D cell histogram ----------------------------
__global__ __launch_bounds__(256) void setup_kernel(
    const float* __restrict__ pos, const float* __restrict__ opac,
    const float* __restrict__ scales, float* __restrict__ accum,
    unsigned* __restrict__ hist)
{
    int i = blockIdx.x * 256 + threadIdx.x;
    float o = opac[i];
    float d = o - 0.5f;
    float s_sp = fabsf(o);
    float s_op = d * d;
    float s_sc = fabsf(scales[3 * i] - 1.0f) + fabsf(scales[3 * i + 1] - 1.0f)
               + fabsf(scales[3 * i + 2] - 1.0f);
    int bx = cellf(pos[3 * i]);
    int by = cellf(pos[3 * i + 1]);
    int bz = cellf(pos[3 * i + 2]);
    atomicAdd(&hist[(bx << 10) | (by << 5) | bz], 1u);
#pragma unroll
    for (int off = 32; off > 0; off >>= 1) {
        s_sp += __shfl_down(s_sp, off, 64);
        s_sc += __shfl_down(s_sc, off, 64);
        s_op += __shfl_down(s_op, off, 64);
    }
    if ((threadIdx.x & 63) == 0) {
        atomicAdd(&accum[0], s_sp);
        atomicAdd(&accum[1], s_sc);
        atomicAdd(&accum[2], s_op);
    }
}

// Exclusive scan over 32768 bins: shfl-based (2 barriers total).
// Also re-zeroes hist in place (it becomes the scatter cnt array).
__global__ __launch_bounds__(1024) void prefix_scan(
    unsigned* __restrict__ hist, unsigned* __restrict__ base)
{
    __shared__ unsigned wsum[16];
    const int t = threadIdx.x;
    const int lane = t & 63, wid = t >> 6;
    unsigned loc[32];
    uint4* h4 = (uint4*)(hist + t * 32);
#pragma unroll
    for (int j = 0; j < 8; ++j) {
        uint4 h = h4[j];
        loc[4 * j + 0] = h.x; loc[4 * j + 1] = h.y;
        loc[4 * j + 2] = h.z; loc[4 * j + 3] = h.w;
    }
    unsigned run = 0;
#pragma unroll
    for (int j = 0; j < 32; ++j) { unsigned v = loc[j]; loc[j] = run; run += v; }
    unsigned inc = run;
#pragma unroll
    for (int off = 1; off < 64; off <<= 1) {
        unsigned v = (unsigned)__shfl_up((int)inc, off, 64);
        if (lane >= off) inc += v;
    }
    if (lane == 63) wsum[wid] = inc;
    __syncthreads();
    if (wid == 0) {
        unsigned w = (lane < 16) ? wsum[lane] : 0u;
#pragma unroll
        for (int off = 1; off < 16; off <<= 1) {
            unsigned v = (unsigned)__shfl_up((int)w, off, 64);
            if (lane >= off) w += v;
        }
        if (lane < 16) wsum[lane] = w;
    }
    __syncthreads();
    const unsigned wbase = (wid > 0) ? wsum[wid - 1] : 0u;
    const unsigned tbase = wbase + inc - run;
    uint4* b4 = (uint4*)(base + t * 32);
#pragma unroll
    for (int j = 0; j < 8; ++j) {
        b4[j] = make_uint4(loc[4 * j] + tbase, loc[4 * j + 1] + tbase,
                           loc[4 * j + 2] + tbase, loc[4 * j + 3] + tbase);
        h4[j] = make_uint4(0u, 0u, 0u, 0u);
    }
    if (t == 1023) base[NBK] = NPTS;
}

__global__ __launch_bounds__(256) void scatter_sorted(
    const float* __restrict__ pos, const float* __restrict__ opac,
    const unsigned* __restrict__ base, unsigned* __restrict__ cnt,
    float4* __restrict__ sorted)
{
    int i = blockIdx.x * 256 + threadIdx.x;
    float x = pos[3 * i], y = pos[3 * i + 1], z = pos[3 * i + 2];
    int b = (cellf(x) << 10) | (cellf(y) << 5) | cellf(z);
    unsigned p = base[b] + atomicAdd(&cnt[b], 1u);
    sorted[p] = make_float4(x, y, z, opac[i]);
}

// ---- fused kNN: bound pass + windowed exact scan + smoothness -------------
// 16 lanes/point (4 points/wave). Heavy-queue admission is aggregated per
// BLOCK (one with-return atomic), smoothness sums go to 64 padded slots
// (one add per wave) -- no same-address atomic bursts.
__global__ __launch_bounds__(256) void knn_main(
    const float4* __restrict__ sorted, const unsigned* __restrict__ base,
    unsigned* __restrict__ r2m, unsigned* __restrict__ qcnt,
    int* __restrict__ queue, float* __restrict__ parts)
{
    __shared__ unsigned hflags;
    __shared__ unsigned qbase;
    if (threadIdx.x == 0) hflags = 0u;
    __syncthreads();

    const int sub = threadIdx.x & 15;
    const int grp = threadIdx.x >> 4;          // group in block (0..15)
    const int wid = threadIdx.x >> 6;          // wave in block (0..3)
    const int s   = blockIdx.x * 16 + grp;

    const float4 me = sorted[s];

    // ---- phase A: bound from the +/-128 cell-order window ----
    unsigned a[TOPK];
#pragma unroll
    for (int k = 0; k < TOPK; ++k) a[k] = 0xFFFFFFFFu;
    {
        const int dir = sub >> 3;               // 0 right, 1 left
        const int start = 1 + (sub & 7) * 16;
#pragma unroll 4
        for (int t = 0; t < 16; ++t) {
            int p = dir ? (s - start - t) : (s + start + t);
            int pc = min(max(p, 0), NPTS - 1);
            float4 c = sorted[pc];
            float dx = c.x - me.x, dy = c.y - me.y, dz = c.z - me.z;
            float d2 = fmaf(dx, dx, fmaf(dy, dy, dz * dz));
            unsigned key = (__float_as_uint(d2) & 0xFFFFC000u) | (unsigned)pc;
            if (p < 0 || p >= NPTS) key = 0xFFFFFFFFu;
            chain_insert(a, key);
        }
    }
    merge_shfl(a, 1); merge_shfl(a, 2); merge_shfl(a, 4); merge_shfl(a, 8);
    const unsigned sentinel = (a[TOPK - 1] & 0xFFFFC000u) + SENT_STEP;
    const float R = sqrtf(__uint_as_float(sentinel)) + 1e-6f;

    const int bxlo = cellf(me.x - R), bxhi = cellf(me.x + R);
    const int bylo = cellf(me.y - R), byhi = cellf(me.y + R);
    const int bzlo = cellf(me.z - R), bzhi = cellf(me.z + R);
    const int nyw   = byhi - bylo + 1;
    const int npair = (bxhi - bxlo + 1) * nyw;

    // per-lane pair iterator constants (division once, then div-free stepping)
    const int q0  = sub / nyw, r0  = sub - q0 * nyw;
    const int q16 = 16 / nyw,  r16 = 16 - q16 * nyw;

    // ---- phase B: classify (lanes strided over column pairs) ----
    unsigned csum = 0;
    {
        int bx = bxlo + q0, byo = r0;
        for (int pi = sub; pi < npair; pi += 16) {
            int cb = (bx << 10) | ((bylo + byo) << 5);
            csum += base[cb + bzhi + 1] - base[cb + bzlo];
            byo += r16; bx += q16;
            if (byo >= nyw) { byo -= nyw; ++bx; }
        }
    }
#pragma unroll
    for (int off = 1; off <= 8; off <<= 1)
        csum += (unsigned)__shfl_xor((int)csum, off, 64);
    const bool heavy = csum > LIGHT_MAX;

    // block-aggregated queue admission: one with-return atomic per block
    if (heavy && sub == 0) atomicOr(&hflags, 1u << grp);
    __syncthreads();
    if (threadIdx.x == 0 && hflags != 0u)
        qbase = atomicAdd(qcnt, (unsigned)__popc(hflags));
    __syncthreads();
    if (heavy && sub == 0) {
        unsigned rank = __popc(hflags & ((1u << grp) - 1u));
        queue[qbase + rank] = s;
        r2m[s] = sentinel;                       // pass sentinel to heavy path
    }

    // ---- phase C: per-lane-parallel scan, next-pair bounds prefetched ----
#pragma unroll
    for (int k = 0; k < TOPK; ++k) a[k] = sentinel;
    if (!heavy) {
        int bx = bxlo + q0, byo = r0;
        int pi = sub;
        unsigned lo = 0, hi = 0;
        if (pi < npair) {
            int cb = (bx << 10) | ((bylo + byo) << 5);
            lo = base[cb + bzlo]; hi = base[cb + bzhi + 1];
        }
        while (pi < npair) {
            const int npi = pi + 16;
            byo += r16; bx += q16;
            if (byo >= nyw) { byo -= nyw; ++bx; }
            unsigned nlo = 0, nhi = 0;
            if (npi < npair) {                   // prefetch next pair's bounds
                int cb = (bx << 10) | ((bylo + byo) << 5);
                nlo = base[cb + bzlo]; nhi = base[cb + bzhi + 1];
            }
            unsigned p = lo;
            for (; p + 1 < hi; p += 2)
                scan2(a, sorted, p, p + 1, (unsigned)s, me.x, me.y, me.z);
            if (p < hi)
                scan1(a, sorted, p, (unsigned)s, me.x, me.y, me.z);
            pi = npi; lo = nlo; hi = nhi;
        }
        merge_shfl(a, 1); merge_shfl(a, 2); merge_shfl(a, 4); merge_shfl(a, 8);
    }

    float v = 0.0f;
    if (!heavy && sub < TOPK) {
        int j = (int)(a[sub] & 0x3FFFu);
        v = fabsf(me.w - sorted[j].w);
    }
    v += __shfl_down(v, 8, 64);
    v += __shfl_down(v, 4, 64);
    v += __shfl_down(v, 2, 64);
    v += __shfl_down(v, 1, 64);
    // wave total from the 4 group leaders (lanes 0,16,32,48)
    float g = (sub == 0) ? v : 0.0f;
    g += __shfl_down(g, 16, 64);
    g += __shfl_down(g, 32, 64);
    if ((threadIdx.x & 63) == 0)
        atomicAdd(&parts[((blockIdx.x * 4 + wid) & (NSLOT - 1)) * 32], g);
}

// ---- heavy path: ONE WAVE per queued point --------------------------------
// 4096 wave slots -> all heavy points concurrent. No barriers, no m-search
// (the box bound is never tighter than the phase-A sentinel). Per-wave
// register accumulation; ONE padded-slot atomic per wave at the end.
__global__ __launch_bounds__(256) void knn_heavy(
    const float4* __restrict__ sorted, const unsigned* __restrict__ r2m,
    const unsigned* __restrict__ base, const unsigned* __restrict__ qcnt,
    const int* __restrict__ queue, float* __restrict__ parts)
{
    const int lane = threadIdx.x & 63;
    const int wave = (blockIdx.x * 256 + threadIdx.x) >> 6;
    const int nq   = (int)*qcnt;

    float wsum = 0.0f;
    for (int qi = wave; qi < nq; qi += HEAVY_GRID * 4) {
        const int s = queue[qi];
        const float4 me = sorted[s];
        const unsigned sentinel = r2m[s];        // already stepped
        const float R = sqrtf(__uint_as_float(sentinel)) + 1e-6f;

        const int bxlo = cellf(me.x - R), bxhi = cellf(me.x + R);
        const int bylo = cellf(me.y - R), byhi = cellf(me.y + R);
        const int bzlo = cellf(me.z - R), bzhi = cellf(me.z + R);
        const int nyw   = byhi - bylo + 1;
        const int npair = (bxhi - bxlo + 1) * nyw;

        unsigned a[TOPK];
#pragma unroll
        for (int k = 0; k < TOPK; ++k) a[k] = sentinel;

        for (int pi = lane; pi < npair; pi += 64) {
            int cbx = bxlo + pi / nyw, cby = bylo + pi % nyw;
            int cb = (cbx << 10) | (cby << 5);
            unsigned lo = base[cb + bzlo], hi = base[cb + bzhi + 1];
            unsigned p = lo;
            for (; p + 1 < hi; p += 2)
                scan2(a, sorted, p, p + 1, (unsigned)s, me.x, me.y, me.z);
            if (p < hi)
                scan1(a, sorted, p, (unsigned)s, me.x, me.y, me.z);
        }

        merge_shfl(a, 1);  merge_shfl(a, 2);  merge_shfl(a, 4);
        merge_shfl(a, 8);  merge_shfl(a, 16); merge_shfl(a, 32);

        float v = 0.0f;
        if (lane < TOPK) {
            int j = (int)(a[lane] & 0x3FFFu);
            v = fabsf(me.w - sorted[j].w);
        }
        v += __shfl_down(v, 8, 64);
        v += __shfl_down(v, 4, 64);
        v += __shfl_down(v, 2, 64);
        v += __shfl_down(v, 1, 64);
        wsum += v;                               // valid at lane 0
    }
    if (lane == 0 && wsum != 0.0f)
        atomicAdd(&parts[(wave & (NSLOT - 1)) * 32], wsum);
}

// ---- combine --------------------------------------------------------------
__global__ void combine(const float* __restrict__ accum,
                        const float* __restrict__ parts,
                        float* __restrict__ out)
{
    const int lane = threadIdx.x;                // 64 threads
    float sm = parts[lane * 32];
#pragma unroll
    for (int off = 32; off > 0; off >>= 1)
        sm += __shfl_down(sm, off, 64);
    if (lane == 0) {
        const float n = (float)NPTS;
        float sparsity = accum[0] / n;
        float scale    = accum[1] / (3.0f * n);
        float opacl    = accum[2] / n;
        float smooth   = sm / (n * 10.0f);
        out[0] = 0.01f * sparsity + 0.1f * smooth + scale + opacl;
    }
}

extern "C" void kernel_launch(void* const* d_in, const int* in_sizes, int n_in,
                              void* d_out, int out_size, void* d_ws, size_t ws_size,
                              hipStream_t stream)
{
    const float* pos    = (const float*)d_in[0];
    const float* opac   = (const float*)d_in[1];
    const float* scales = (const float*)d_in[2];
    float* out = (float*)d_out;

    char* ws = (char*)d_ws;
    float*    accum  = (float*)ws;
    unsigned* qcnt   = (unsigned*)(ws + 16);
    float*    parts  = (float*)(ws + 128);
    unsigned* histcnt= (unsigned*)(ws + 8448);     // hist -> cnt -> queue
    int*      queue  = (int*)(ws + 8448);
    unsigned* base   = (unsigned*)(ws + 139520);
    unsigned* r2m    = (unsigned*)(ws + 270720);
    float4*   sorted = (float4*)(ws + 336256);

    hipMemsetAsync(ws, 0, 139520, stream);

    setup_kernel  <<<NPTS / 256, 256, 0, stream>>>(pos, opac, scales, accum, histcnt);
    prefix_scan   <<<1, 1024, 0, stream>>>(histcnt, base);
    scatter_sorted<<<NPTS / 256, 256, 0, stream>>>(pos, opac, base, histcnt, sorted);
    knn_main      <<<NPTS / 16, 256, 0, stream>>>(sorted, base, r2m, qcnt, queue, parts);
    knn_heavy     <<<HEAVY_GRID, 256, 0, stream>>>(sorted, r2m, base, qcnt, queue, parts);
    combine       <<<1, 64, 0, stream>>>(accum, parts, out);
}

// Round 8
// 136.599 us; speedup vs baseline: 1.5067x; 1.0605x over previous
//
#include <hip/hip_runtime.h>
#include <stdint.h>

// N=16384 points, K=10 (fixed by setup_inputs).
#define NPTS   16384
#define TOPK   10
#define NBX    32                 // 32x32x32 cells over [-5,5]^3
#define NBK    (32 * 32 * 32)
#define XMIN   (-5.0f)
#define INVBW  (3.2f)             // 32 / 10.0
#define SENT_STEP 0x4000u         // one ulp at masked-key granularity (= idx field)
#define LIGHT_MAX 512u            // candidate cap for the 16-lane path
#define HEAVY_GRID 1024           // x4 waves = 4096 wave slots
#define NSLOT  64                 // padded accumulator rows (128 B apart)

// ws layout (bytes):
//   128     parts[NSLOT][32] floats; row r: [0]=sparsity [1]=scale [2]=opacity
//           [3]=smooth                                  [128, 8320)
//   8448    hist[NBK] uint -> re-zeroed by scan, reused as cnt  [8448, 139520)
//   139520  base[NBK+1] uint                            [139520, 270596)
//   270720  r2m[NPTS] uint: 0 = light, else stepped sentinel (heavy flag)
//   336256  sorted[NPTS] float4 (x,y,z,opacity) cell-order
// memset zeroes [0, 139520). r2m fully written by knn_main (no memset need).
// NO with-return atomics and NO single-address atomic bursts anywhere.

__device__ __forceinline__ unsigned umin_(unsigned a, unsigned b) { return a < b ? a : b; }
__device__ __forceinline__ unsigned umax_(unsigned a, unsigned b) { return a > b ? a : b; }

// Branchless ascending insert (19 independent min/max).
__device__ __forceinline__ void chain_insert(unsigned a[TOPK], unsigned key) {
#pragma unroll
    for (int k = TOPK - 1; k > 0; --k) a[k] = umin_(umax_(a[k - 1], key), a[k]);
    a[0] = umin_(a[0], key);
}

__device__ __forceinline__ void ce_(unsigned &x, unsigned &y) {
    unsigned lo = umin_(x, y); y = umax_(x, y); x = lo;
}

// Bitonic merge network for a length-10 bitonic sequence (15 CEs).
__device__ __forceinline__ void bitonic10(unsigned a[TOPK]) {
    ce_(a[0], a[8]); ce_(a[1], a[9]);
    ce_(a[0], a[4]); ce_(a[1], a[5]); ce_(a[2], a[6]); ce_(a[3], a[7]);
    ce_(a[0], a[2]); ce_(a[1], a[3]); ce_(a[4], a[6]); ce_(a[5], a[7]);
    ce_(a[0], a[1]); ce_(a[2], a[3]); ce_(a[4], a[5]); ce_(a[6], a[7]); ce_(a[8], a[9]);
}

// Merge two sorted 10-lists: ours + partner lane's (halver + bitonic net).
__device__ __forceinline__ void merge_shfl(unsigned a[TOPK], int w) {
    unsigned b[TOPK];
#pragma unroll
    for (int k = 0; k < TOPK; ++k) b[k] = (unsigned)__shfl_xor((int)a[k], w, 64);
#pragma unroll
    for (int k = 0; k < TOPK; ++k) a[k] = umin_(a[k], b[TOPK - 1 - k]);
    bitonic10(a);
}

// Process two candidates with both loads issued before either use.
__device__ __forceinline__ void scan2(
    unsigned a[TOPK], const float4* __restrict__ sorted,
    unsigned p0, unsigned p1, unsigned s, float mx, float my, float mz)
{
    float4 c0 = sorted[p0];
    float4 c1 = sorted[p1];
    float dx0 = c0.x - mx, dy0 = c0.y - my, dz0 = c0.z - mz;
    float dx1 = c1.x - mx, dy1 = c1.y - my, dz1 = c1.z - mz;
    float d20 = fmaf(dx0, dx0, fmaf(dy0, dy0, dz0 * dz0));
    float d21 = fmaf(dx1, dx1, fmaf(dy1, dy1, dz1 * dz1));
    unsigned k0 = (__float_as_uint(d20) & 0xFFFFC000u) | p0;
    unsigned k1 = (__float_as_uint(d21) & 0xFFFFC000u) | p1;
    if (p0 == s) k0 = 0xFFFFFFFFu;
    if (p1 == s) k1 = 0xFFFFFFFFu;
    unsigned kmin = umin_(k0, k1), kmax = umax_(k0, k1);
    if (kmin < a[TOPK - 1]) {
        chain_insert(a, kmin);
        if (kmax < a[TOPK - 1]) chain_insert(a, kmax);
    }
}

__device__ __forceinline__ void scan1(
    unsigned a[TOPK], const float4* __restrict__ sorted,
    unsigned p, unsigned s, float mx, float my, float mz)
{
    float4 c = sorted[p];
    float dx = c.x - mx, dy = c.y - my, dz = c.z - mz;
    float d2 = fmaf(dx, dx, fmaf(dy, dy, dz * dz));
    unsigned key = (__float_as_uint(d2) & 0xFFFFC000u) | p;
    if (p == s) key = 0xFFFFFFFFu;
    if (key < a[TOPK - 1]) chain_insert(a, key);
}

__device__ __forceinline__ int cellf(float v) {
    int b = (int)((v - XMIN) * INVBW);
    return min(max(b, 0), NBX - 1);
}

// ---- fused trivial losses + 3-D cell histogram ----------------------------
__global__ __launch_bounds__(256) void setup_kernel(
    const float* __restrict__ pos, const float* __restrict__ opac,
    const float* __restrict__ scales, float* __restrict__ parts,
    unsigned* __restrict__ hist)
{
    int i = blockIdx.x * 256 + threadIdx.x;
    float o = opac[i];
    float d = o - 0.5f;
    float s_sp = fabsf(o);
    float s_op = d * d;
    float s_sc = fabsf(scales[3 * i] - 1.0f) + fabsf(scales[3 * i + 1] - 1.0f)
               + fabsf(scales[3 * i + 2] - 1.0f);
    int bx = cellf(pos[3 * i]);
    int by = cellf(pos[3 * i + 1]);
    int bz = cellf(pos[3 * i + 2]);
    atomicAdd(&hist[(bx << 10) | (by << 5) | bz], 1u);
#pragma unroll
    for (int off = 32; off > 0; off >>= 1) {
        s_sp += __shfl_down(s_sp, off, 64);
        s_sc += __shfl_down(s_sc, off, 64);
        s_op += __shfl_down(s_op, off, 64);
    }
    if ((threadIdx.x & 63) == 0) {
        const int row = (blockIdx.x * 4 + (threadIdx.x >> 6)) & (NSLOT - 1);
        atomicAdd(&parts[row * 32 + 0], s_sp);
        atomicAdd(&parts[row * 32 + 1], s_sc);
        atomicAdd(&parts[row * 32 + 2], s_op);
    }
}

// Exclusive scan over 32768 bins: shfl-based (2 barriers total).
// Also re-zeroes hist in place (it becomes the scatter cnt array).
__global__ __launch_bounds__(1024) void prefix_scan(
    unsigned* __restrict__ hist, unsigned* __restrict__ base)
{
    __shared__ unsigned wsum[16];
    const int t = threadIdx.x;
    const int lane = t & 63, wid = t >> 6;
    unsigned loc[32];
    uint4* h4 = (uint4*)(hist + t * 32);
#pragma unroll
    for (int j = 0; j < 8; ++j) {
        uint4 h = h4[j];
        loc[4 * j + 0] = h.x; loc[4 * j + 1] = h.y;
        loc[4 * j + 2] = h.z; loc[4 * j + 3] = h.w;
    }
    unsigned run = 0;
#pragma unroll
    for (int j = 0; j < 32; ++j) { unsigned v = loc[j]; loc[j] = run; run += v; }
    unsigned inc = run;
#pragma unroll
    for (int off = 1; off < 64; off <<= 1) {
        unsigned v = (unsigned)__shfl_up((int)inc, off, 64);
        if (lane >= off) inc += v;
    }
    if (lane == 63) wsum[wid] = inc;
    __syncthreads();
    if (wid == 0) {
        unsigned w = (lane < 16) ? wsum[lane] : 0u;
#pragma unroll
        for (int off = 1; off < 16; off <<= 1) {
            unsigned v = (unsigned)__shfl_up((int)w, off, 64);
            if (lane >= off) w += v;
        }
        if (lane < 16) wsum[lane] = w;
    }
    __syncthreads();
    const unsigned wbase = (wid > 0) ? wsum[wid - 1] : 0u;
    const unsigned tbase = wbase + inc - run;
    uint4* b4 = (uint4*)(base + t * 32);
#pragma unroll
    for (int j = 0; j < 8; ++j) {
        b4[j] = make_uint4(loc[4 * j] + tbase, loc[4 * j + 1] + tbase,
                           loc[4 * j + 2] + tbase, loc[4 * j + 3] + tbase);
        h4[j] = make_uint4(0u, 0u, 0u, 0u);
    }
    if (t == 1023) base[NBK] = NPTS;
}

__global__ __launch_bounds__(256) void scatter_sorted(
    const float* __restrict__ pos, const float* __restrict__ opac,
    const unsigned* __restrict__ base, unsigned* __restrict__ cnt,
    float4* __restrict__ sorted)
{
    int i = blockIdx.x * 256 + threadIdx.x;
    float x = pos[3 * i], y = pos[3 * i + 1], z = pos[3 * i + 2];
    int b = (cellf(x) << 10) | (cellf(y) << 5) | cellf(z);
    unsigned p = base[b] + atomicAdd(&cnt[b], 1u);
    sorted[p] = make_float4(x, y, z, opac[i]);
}

// ---- fused kNN: bound pass + windowed exact scan + smoothness -------------
// 16 lanes/point (4 points/wave). NO barriers, NO queue: heavy points are
// flagged via r2m[s] = sentinel (light: 0); knn_heavy sweeps the flags.
__global__ __launch_bounds__(256) void knn_main(
    const float4* __restrict__ sorted, const unsigned* __restrict__ base,
    unsigned* __restrict__ r2m, float* __restrict__ parts)
{
    const int sub = threadIdx.x & 15;
    const int wid = threadIdx.x >> 6;
    const int s   = blockIdx.x * 16 + (threadIdx.x >> 4);

    const float4 me = sorted[s];

    // ---- phase A: bound from the +/-128 cell-order window ----
    unsigned a[TOPK];
#pragma unroll
    for (int k = 0; k < TOPK; ++k) a[k] = 0xFFFFFFFFu;
    {
        const int dir = sub >> 3;               // 0 right, 1 left
        const int start = 1 + (sub & 7) * 16;
#pragma unroll 4
        for (int t = 0; t < 16; ++t) {
            int p = dir ? (s - start - t) : (s + start + t);
            int pc = min(max(p, 0), NPTS - 1);
            float4 c = sorted[pc];
            float dx = c.x - me.x, dy = c.y - me.y, dz = c.z - me.z;
            float d2 = fmaf(dx, dx, fmaf(dy, dy, dz * dz));
            unsigned key = (__float_as_uint(d2) & 0xFFFFC000u) | (unsigned)pc;
            if (p < 0 || p >= NPTS) key = 0xFFFFFFFFu;
            chain_insert(a, key);
        }
    }
    merge_shfl(a, 1); merge_shfl(a, 2); merge_shfl(a, 4); merge_shfl(a, 8);
    const unsigned sentinel = (a[TOPK - 1] & 0xFFFFC000u) + SENT_STEP;
    const float R = sqrtf(__uint_as_float(sentinel)) + 1e-6f;

    const int bxlo = cellf(me.x - R), bxhi = cellf(me.x + R);
    const int bylo = cellf(me.y - R), byhi = cellf(me.y + R);
    const int bzlo = cellf(me.z - R), bzhi = cellf(me.z + R);
    const int nyw   = byhi - bylo + 1;
    const int npair = (bxhi - bxlo + 1) * nyw;

    // per-lane pair iterator constants (division once, then div-free stepping)
    const int q0  = sub / nyw, r0  = sub - q0 * nyw;
    const int q16 = 16 / nyw,  r16 = 16 - q16 * nyw;

    // ---- phase B: classify (lanes strided over column pairs) ----
    unsigned csum = 0;
    {
        int bx = bxlo + q0, byo = r0;
        for (int pi = sub; pi < npair; pi += 16) {
            int cb = (bx << 10) | ((bylo + byo) << 5);
            csum += base[cb + bzhi + 1] - base[cb + bzlo];
            byo += r16; bx += q16;
            if (byo >= nyw) { byo -= nyw; ++bx; }
        }
    }
#pragma unroll
    for (int off = 1; off <= 8; off <<= 1)
        csum += (unsigned)__shfl_xor((int)csum, off, 64);
    const bool heavy = csum > LIGHT_MAX;
    if (sub == 0) r2m[s] = heavy ? sentinel : 0u;   // flag for knn_heavy

    // ---- phase C: per-lane-parallel scan, next-pair bounds prefetched ----
#pragma unroll
    for (int k = 0; k < TOPK; ++k) a[k] = sentinel;
    if (!heavy) {
        int bx = bxlo + q0, byo = r0;
        int pi = sub;
        unsigned lo = 0, hi = 0;
        if (pi < npair) {
            int cb = (bx << 10) | ((bylo + byo) << 5);
            lo = base[cb + bzlo]; hi = base[cb + bzhi + 1];
        }
        while (pi < npair) {
            const int npi = pi + 16;
            byo += r16; bx += q16;
            if (byo >= nyw) { byo -= nyw; ++bx; }
            unsigned nlo = 0, nhi = 0;
            if (npi < npair) {                   // prefetch next pair's bounds
                int cb = (bx << 10) | ((bylo + byo) << 5);
                nlo = base[cb + bzlo]; nhi = base[cb + bzhi + 1];
            }
            unsigned p = lo;
            for (; p + 1 < hi; p += 2)
                scan2(a, sorted, p, p + 1, (unsigned)s, me.x, me.y, me.z);
            if (p < hi)
                scan1(a, sorted, p, (unsigned)s, me.x, me.y, me.z);
            pi = npi; lo = nlo; hi = nhi;
        }
        merge_shfl(a, 1); merge_shfl(a, 2); merge_shfl(a, 4); merge_shfl(a, 8);
    }

    float v = 0.0f;
    if (!heavy && sub < TOPK) {
        int j = (int)(a[sub] & 0x3FFFu);
        v = fabsf(me.w - sorted[j].w);
    }
    v += __shfl_down(v, 8, 64);
    v += __shfl_down(v, 4, 64);
    v += __shfl_down(v, 2, 64);
    v += __shfl_down(v, 1, 64);
    // wave total from the 4 group leaders (lanes 0,16,32,48)
    float g = (sub == 0) ? v : 0.0f;
    g += __shfl_down(g, 16, 64);
    g += __shfl_down(g, 32, 64);
    if ((threadIdx.x & 63) == 0) {
        const int row = (blockIdx.x * 4 + wid) & (NSLOT - 1);
        atomicAdd(&parts[row * 32 + 3], g);
    }
}

// ---- heavy path: flag sweep, ONE WAVE per heavy point ---------------------
// Waves grid-stride all 16384 points and skip r2m[s]==0 (wave-uniform
// broadcast load). No queue, no with-return atomics, no barriers.
__global__ __launch_bounds__(256) void knn_heavy(
    const float4* __restrict__ sorted, const unsigned* __restrict__ r2m,
    const unsigned* __restrict__ base, float* __restrict__ parts)
{
    const int lane = threadIdx.x & 63;
    const int wave = (blockIdx.x * 256 + threadIdx.x) >> 6;
    const int nw   = HEAVY_GRID * 4;

    float wsum = 0.0f;
    for (int s = wave; s < NPTS; s += nw) {
        const unsigned sentinel = r2m[s];
        if (sentinel == 0u) continue;            // light point, done in main
        const float4 me = sorted[s];
        const float R = sqrtf(__uint_as_float(sentinel)) + 1e-6f;

        const int bxlo = cellf(me.x - R), bxhi = cellf(me.x + R);
        const int bylo = cellf(me.y - R), byhi = cellf(me.y + R);
        const int bzlo = cellf(me.z - R), bzhi = cellf(me.z + R);
        const int nyw   = byhi - bylo + 1;
        const int npair = (bxhi - bxlo + 1) * nyw;

        unsigned a[TOPK];
#pragma unroll
        for (int k = 0; k < TOPK; ++k) a[k] = sentinel;

        for (int pi = lane; pi < npair; pi += 64) {
            int cbx = bxlo + pi / nyw, cby = bylo + pi % nyw;
            int cb = (cbx << 10) | (cby << 5);
            unsigned lo = base[cb + bzlo], hi = base[cb + bzhi + 1];
            unsigned p = lo;
            for (; p + 1 < hi; p += 2)
                scan2(a, sorted, p, p + 1, (unsigned)s, me.x, me.y, me.z);
            if (p < hi)
                scan1(a, sorted, p, (unsigned)s, me.x, me.y, me.z);
        }

        merge_shfl(a, 1);  merge_shfl(a, 2);  merge_shfl(a, 4);
        merge_shfl(a, 8);  merge_shfl(a, 16); merge_shfl(a, 32);

        float v = 0.0f;
        if (lane < TOPK) {
            int j = (int)(a[lane] & 0x3FFFu);
            v = fabsf(me.w - sorted[j].w);
        }
        v += __shfl_down(v, 8, 64);
        v += __shfl_down(v, 4, 64);
        v += __shfl_down(v, 2, 64);
        v += __shfl_down(v, 1, 64);
        wsum += v;                               // valid at lane 0
    }
    if (lane == 0 && wsum != 0.0f)
        atomicAdd(&parts[(wave & (NSLOT - 1)) * 32 + 3], wsum);
}

// ---- combine --------------------------------------------------------------
__global__ void combine(const float* __restrict__ parts, float* __restrict__ out)
{
    const int lane = threadIdx.x;                // 64 threads
    float4 p = *(const float4*)(parts + lane * 32);
    float sp = p.x, sc = p.y, op = p.z, sm = p.w;
#pragma unroll
    for (int off = 32; off > 0; off >>= 1) {
        sp += __shfl_down(sp, off, 64);
        sc += __shfl_down(sc, off, 64);
        op += __shfl_down(op, off, 64);
        sm += __shfl_down(sm, off, 64);
    }
    if (lane == 0) {
        const float n = (float)NPTS;
        out[0] = 0.01f * (sp / n) + 0.1f * (sm / (n * 10.0f))
               + sc / (3.0f * n) + op / n;
    }
}

extern "C" void kernel_launch(void* const* d_in, const int* in_sizes, int n_in,
                              void* d_out, int out_size, void* d_ws, size_t ws_size,
                              hipStream_t stream)
{
    const float* pos    = (const float*)d_in[0];
    const float* opac   = (const float*)d_in[1];
    const float* scales = (const float*)d_in[2];
    float* out = (float*)d_out;

    char* ws = (char*)d_ws;
    float*    parts  = (float*)(ws + 128);
    unsigned* histcnt= (unsigned*)(ws + 8448);     // hist -> cnt
    unsigned* base   = (unsigned*)(ws + 139520);
    unsigned* r2m    = (unsigned*)(ws + 270720);
    float4*   sorted = (float4*)(ws + 336256);

    hipMemsetAsync(ws, 0, 139520, stream);

    setup_kernel  <<<NPTS / 256, 256, 0, stream>>>(pos, opac, scales, parts, histcnt);
    prefix_scan   <<<1, 1024, 0, stream>>>(histcnt, base);
    scatter_sorted<<<NPTS / 256, 256, 0, stream>>>(pos, opac, base, histcnt, sorted);
    knn_main      <<<NPTS / 16, 256, 0, stream>>>(sorted, base, r2m, parts);
    knn_heavy     <<<HEAVY_GRID, 256, 0, stream>>>(sorted, r2m, base, parts);
    combine       <<<1, 64, 0, stream>>>(parts, out);
}

// Round 9
// 133.618 us; speedup vs baseline: 1.5404x; 1.0223x over previous
//
#include <hip/hip_runtime.h>
#include <stdint.h>

// N=16384 points, K=10 (fixed by setup_inputs).
#define NPTS   16384
#define TOPK   10
#define NBX    32                 // 32x32x32 cells over [-5,5]^3
#define NBK    (32 * 32 * 32)
#define XMIN   (-5.0f)
#define INVBW  (3.2f)             // 32 / 10.0
#define SENT_STEP 0x4000u         // one ulp at masked-key granularity (= idx field)
#define NSLOT  256                // padded accumulator rows (128 B apart)

// ws layout (bytes):
//   128     parts[NSLOT][32] floats; row: [0]=sparsity [1]=scale [2]=opacity
//           [3]=smooth                                  [128, 32896)
//   33024   hist[NBK] uint -> re-zeroed by scan, reused as cnt [33024, 164096)
//   164096  base[NBK+1] uint                            [164096, 295172)
//   295296  sorted[NPTS] float4 (x,y,z,opacity) cell-order
// memset zeroes [0, 164096). No with-return atomics anywhere; all float
// accumulation goes to padded rows (<= 64 RMWs per address).

__device__ __forceinline__ unsigned umin_(unsigned a, unsigned b) { return a < b ? a : b; }
__device__ __forceinline__ unsigned umax_(unsigned a, unsigned b) { return a > b ? a : b; }

// Branchless ascending insert (19 independent min/max).
__device__ __forceinline__ void chain_insert(unsigned a[TOPK], unsigned key) {
#pragma unroll
    for (int k = TOPK - 1; k > 0; --k) a[k] = umin_(umax_(a[k - 1], key), a[k]);
    a[0] = umin_(a[0], key);
}

__device__ __forceinline__ void ce_(unsigned &x, unsigned &y) {
    unsigned lo = umin_(x, y); y = umax_(x, y); x = lo;
}

// Bitonic merge network for a length-10 bitonic sequence (15 CEs).
__device__ __forceinline__ void bitonic10(unsigned a[TOPK]) {
    ce_(a[0], a[8]); ce_(a[1], a[9]);
    ce_(a[0], a[4]); ce_(a[1], a[5]); ce_(a[2], a[6]); ce_(a[3], a[7]);
    ce_(a[0], a[2]); ce_(a[1], a[3]); ce_(a[4], a[6]); ce_(a[5], a[7]);
    ce_(a[0], a[1]); ce_(a[2], a[3]); ce_(a[4], a[5]); ce_(a[6], a[7]); ce_(a[8], a[9]);
}

// Merge two sorted 10-lists: ours + partner lane's (halver + bitonic net).
__device__ __forceinline__ void merge_shfl(unsigned a[TOPK], int w) {
    unsigned b[TOPK];
#pragma unroll
    for (int k = 0; k < TOPK; ++k) b[k] = (unsigned)__shfl_xor((int)a[k], w, 64);
#pragma unroll
    for (int k = 0; k < TOPK; ++k) a[k] = umin_(a[k], b[TOPK - 1 - k]);
    bitonic10(a);
}

__device__ __forceinline__ void scan1(
    unsigned a[TOPK], const float4* __restrict__ sorted,
    unsigned p, unsigned s, float mx, float my, float mz)
{
    float4 c = sorted[p];
    float dx = c.x - mx, dy = c.y - my, dz = c.z - mz;
    float d2 = fmaf(dx, dx, fmaf(dy, dy, dz * dz));
    unsigned key = (__float_as_uint(d2) & 0xFFFFC000u) | p;
    if (p == s) key = 0xFFFFFFFFu;
    if (key < a[TOPK - 1]) chain_insert(a, key);
}

__device__ __forceinline__ int cellf(float v) {
    int b = (int)((v - XMIN) * INVBW);
    return min(max(b, 0), NBX - 1);
}

// ---- fused trivial losses + 3-D cell histogram ----------------------------
__global__ __launch_bounds__(256) void setup_kernel(
    const float* __restrict__ pos, const float* __restrict__ opac,
    const float* __restrict__ scales, float* __restrict__ parts,
    unsigned* __restrict__ hist)
{
    int i = blockIdx.x * 256 + threadIdx.x;
    float o = opac[i];
    float d = o - 0.5f;
    float s_sp = fabsf(o);
    float s_op = d * d;
    float s_sc = fabsf(scales[3 * i] - 1.0f) + fabsf(scales[3 * i + 1] - 1.0f)
               + fabsf(scales[3 * i + 2] - 1.0f);
    int bx = cellf(pos[3 * i]);
    int by = cellf(pos[3 * i + 1]);
    int bz = cellf(pos[3 * i + 2]);
    atomicAdd(&hist[(bx << 10) | (by << 5) | bz], 1u);
#pragma unroll
    for (int off = 32; off > 0; off >>= 1) {
        s_sp += __shfl_down(s_sp, off, 64);
        s_sc += __shfl_down(s_sc, off, 64);
        s_op += __shfl_down(s_op, off, 64);
    }
    if ((threadIdx.x & 63) == 0) {
        const int row = (blockIdx.x * 4 + (threadIdx.x >> 6)) & (NSLOT - 1);
        atomicAdd(&parts[row * 32 + 0], s_sp);
        atomicAdd(&parts[row * 32 + 1], s_sc);
        atomicAdd(&parts[row * 32 + 2], s_op);
    }
}

// Exclusive scan over 32768 bins: shfl-based (2 barriers total).
// Also re-zeroes hist in place (it becomes the scatter cnt array).
__global__ __launch_bounds__(1024) void prefix_scan(
    unsigned* __restrict__ hist, unsigned* __restrict__ base)
{
    __shared__ unsigned wsum[16];
    const int t = threadIdx.x;
    const int lane = t & 63, wid = t >> 6;
    unsigned loc[32];
    uint4* h4 = (uint4*)(hist + t * 32);
#pragma unroll
    for (int j = 0; j < 8; ++j) {
        uint4 h = h4[j];
        loc[4 * j + 0] = h.x; loc[4 * j + 1] = h.y;
        loc[4 * j + 2] = h.z; loc[4 * j + 3] = h.w;
    }
    unsigned run = 0;
#pragma unroll
    for (int j = 0; j < 32; ++j) { unsigned v = loc[j]; loc[j] = run; run += v; }
    unsigned inc = run;
#pragma unroll
    for (int off = 1; off < 64; off <<= 1) {
        unsigned v = (unsigned)__shfl_up((int)inc, off, 64);
        if (lane >= off) inc += v;
    }
    if (lane == 63) wsum[wid] = inc;
    __syncthreads();
    if (wid == 0) {
        unsigned w = (lane < 16) ? wsum[lane] : 0u;
#pragma unroll
        for (int off = 1; off < 16; off <<= 1) {
            unsigned v = (unsigned)__shfl_up((int)w, off, 64);
            if (lane >= off) w += v;
        }
        if (lane < 16) wsum[lane] = w;
    }
    __syncthreads();
    const unsigned wbase = (wid > 0) ? wsum[wid - 1] : 0u;
    const unsigned tbase = wbase + inc - run;
    uint4* b4 = (uint4*)(base + t * 32);
#pragma unroll
    for (int j = 0; j < 8; ++j) {
        b4[j] = make_uint4(loc[4 * j] + tbase, loc[4 * j + 1] + tbase,
                           loc[4 * j + 2] + tbase, loc[4 * j + 3] + tbase);
        h4[j] = make_uint4(0u, 0u, 0u, 0u);
    }
    if (t == 1023) base[NBK] = NPTS;
}

__global__ __launch_bounds__(256) void scatter_sorted(
    const float* __restrict__ pos, const float* __restrict__ opac,
    const unsigned* __restrict__ base, unsigned* __restrict__ cnt,
    float4* __restrict__ sorted)
{
    int i = blockIdx.x * 256 + threadIdx.x;
    float x = pos[3 * i], y = pos[3 * i + 1], z = pos[3 * i + 2];
    int b = (cellf(x) << 10) | (cellf(y) << 5) | cellf(z);
    unsigned p = base[b] + atomicAdd(&cnt[b], 1u);
    sorted[p] = make_float4(x, y, z, opac[i]);
}

// ---- unified kNN: ONE WAVE per point --------------------------------------
// Phase A: top-10 bound of the +/-128 cell-order window (4 candidates/lane,
//   6-level merge) -> sentinel (strict upper bound on the true 10-NN key).
// Phase B: ALL column-pair bounds loaded lane-parallel into registers (64 per
//   round), then a wave-uniform serial pair loop reads them via shfl -- no
//   dependent base[]->candidate chain, empty pairs cost ~10 cycles.
// Phase C: 64-lane z-run scan gated by the sentinel, 6-level merge,
//   smoothness gather, one padded-slot atomic per wave.
__global__ __launch_bounds__(256) void knn_all(
    const float4* __restrict__ sorted, const unsigned* __restrict__ base,
    float* __restrict__ parts)
{
    const int lane = threadIdx.x & 63;
    const int s    = (blockIdx.x * 256 + threadIdx.x) >> 6;   // wave id = point

    const float4 me = sorted[s];

    // ---- phase A: bound ----
    unsigned a[TOPK];
#pragma unroll
    for (int k = 0; k < TOPK; ++k) a[k] = 0xFFFFFFFFu;
    {
        const int dir = lane >> 5;              // 0 right, 1 left
        const int start = 1 + (lane & 31) * 4;
#pragma unroll
        for (int t = 0; t < 4; ++t) {
            int p = dir ? (s - start - t) : (s + start + t);
            int pc = min(max(p, 0), NPTS - 1);
            float4 c = sorted[pc];
            float dx = c.x - me.x, dy = c.y - me.y, dz = c.z - me.z;
            float d2 = fmaf(dx, dx, fmaf(dy, dy, dz * dz));
            unsigned key = (__float_as_uint(d2) & 0xFFFFC000u) | (unsigned)pc;
            if (p < 0 || p >= NPTS) key = 0xFFFFFFFFu;
            chain_insert(a, key);
        }
    }
    merge_shfl(a, 1);  merge_shfl(a, 2);  merge_shfl(a, 4);
    merge_shfl(a, 8);  merge_shfl(a, 16); merge_shfl(a, 32);
    const unsigned sentinel = (a[TOPK - 1] & 0xFFFFC000u) + SENT_STEP;
    const float R = sqrtf(__uint_as_float(sentinel)) + 1e-6f;

    const int bxlo = cellf(me.x - R), bxhi = cellf(me.x + R);
    const int bylo = cellf(me.y - R), byhi = cellf(me.y + R);
    const int bzlo = cellf(me.z - R), bzhi = cellf(me.z + R);
    const int nyw   = byhi - bylo + 1;
    const int npair = (bxhi - bxlo + 1) * nyw;

    // ---- phase B/C: lane-parallel bounds + wave-uniform pair scan ----
#pragma unroll
    for (int k = 0; k < TOPK; ++k) a[k] = sentinel;

    for (int cbase = 0; cbase < npair; cbase += 64) {
        const int cnum = min(64, npair - cbase);
        unsigned mylo = 0, myhi = 0;
        const int pi = cbase + lane;
        if (pi < npair) {
            const int qx = pi / nyw;
            const int cb = ((bxlo + qx) << 10) | ((bylo + pi - qx * nyw) << 5);
            mylo = base[cb + bzlo];
            myhi = base[cb + bzhi + 1];
        }
        for (int j = 0; j < cnum; ++j) {
            const unsigned lo = (unsigned)__shfl((int)mylo, j, 64);
            const unsigned hi = (unsigned)__shfl((int)myhi, j, 64);
            for (unsigned p = lo + lane; p < hi; p += 64)
                scan1(a, sorted, p, (unsigned)s, me.x, me.y, me.z);
        }
    }

    merge_shfl(a, 1);  merge_shfl(a, 2);  merge_shfl(a, 4);
    merge_shfl(a, 8);  merge_shfl(a, 16); merge_shfl(a, 32);

    float v = 0.0f;
    if (lane < TOPK) {
        int j = (int)(a[lane] & 0x3FFFu);
        v = fabsf(me.w - sorted[j].w);
    }
    v += __shfl_down(v, 8, 64);
    v += __shfl_down(v, 4, 64);
    v += __shfl_down(v, 2, 64);
    v += __shfl_down(v, 1, 64);
    if (lane == 0)
        atomicAdd(&parts[(s & (NSLOT - 1)) * 32 + 3], v);
}

// ---- combine --------------------------------------------------------------
__global__ void combine(const float* __restrict__ parts, float* __restrict__ out)
{
    const int lane = threadIdx.x;                // 64 threads
    float sp = 0.0f, sc = 0.0f, op = 0.0f, sm = 0.0f;
#pragma unroll
    for (int r = 0; r < NSLOT / 64; ++r) {
        float4 p = *(const float4*)(parts + (r * 64 + lane) * 32);
        sp += p.x; sc += p.y; op += p.z; sm += p.w;
    }
#pragma unroll
    for (int off = 32; off > 0; off >>= 1) {
        sp += __shfl_down(sp, off, 64);
        sc += __shfl_down(sc, off, 64);
        op += __shfl_down(op, off, 64);
        sm += __shfl_down(sm, off, 64);
    }
    if (lane == 0) {
        const float n = (float)NPTS;
        out[0] = 0.01f * (sp / n) + 0.1f * (sm / (n * 10.0f))
               + sc / (3.0f * n) + op / n;
    }
}

extern "C" void kernel_launch(void* const* d_in, const int* in_sizes, int n_in,
                              void* d_out, int out_size, void* d_ws, size_t ws_size,
                              hipStream_t stream)
{
    const float* pos    = (const float*)d_in[0];
    const float* opac   = (const float*)d_in[1];
    const float* scales = (const float*)d_in[2];
    float* out = (float*)d_out;

    char* ws = (char*)d_ws;
    float*    parts  = (float*)(ws + 128);
    unsigned* histcnt= (unsigned*)(ws + 33024);    // hist -> cnt
    unsigned* base   = (unsigned*)(ws + 164096);
    float4*   sorted = (float4*)(ws + 295296);

    hipMemsetAsync(ws, 0, 164096, stream);

    setup_kernel  <<<NPTS / 256, 256, 0, stream>>>(pos, opac, scales, parts, histcnt);
    prefix_scan   <<<1, 1024, 0, stream>>>(histcnt, base);
    scatter_sorted<<<NPTS / 256, 256, 0, stream>>>(pos, opac, base, histcnt, sorted);
    knn_all       <<<NPTS / 4, 256, 0, stream>>>(sorted, base, parts);
    combine       <<<1, 64, 0, stream>>>(parts, out);
}

// Round 10
// 112.775 us; speedup vs baseline: 1.8250x; 1.1848x over previous
//
#include <hip/hip_runtime.h>
#include <stdint.h>

// N=16384 points, K=10 (fixed by setup_inputs).
#define NPTS   16384
#define TOPK   10
#define NBX    32                 // 32x32x32 cells over [-5,5]^3
#define NBK    (32 * 32 * 32)
#define XMIN   (-5.0f)
#define INVBW  (3.2f)             // 32 / 10.0
#define SENT_STEP 0x4000u         // one ulp at masked-key granularity (= idx field)
#define NSLOT  256                // padded accumulator rows (128 B apart)

// ws layout (bytes):
//   128     parts[NSLOT][32] floats; row: [0]=sparsity [1]=scale [2]=opacity
//           [3]=smooth                                  [128, 32896)
//   33024   hist[NBK] uint -> re-zeroed by scan, reused as cnt [33024, 164096)
//   164096  base[NBK+1] uint                            [164096, 295172)
//   295296  sorted[NPTS] float4 (x,y,z,opacity) cell-order
// memset zeroes [0, 164096). No with-return atomics anywhere; all float
// accumulation goes to padded rows (<= 64 RMWs per address).

__device__ __forceinline__ unsigned umin_(unsigned a, unsigned b) { return a < b ? a : b; }
__device__ __forceinline__ unsigned umax_(unsigned a, unsigned b) { return a > b ? a : b; }

// Branchless ascending insert (19 independent min/max).
__device__ __forceinline__ void chain_insert(unsigned a[TOPK], unsigned key) {
#pragma unroll
    for (int k = TOPK - 1; k > 0; --k) a[k] = umin_(umax_(a[k - 1], key), a[k]);
    a[0] = umin_(a[0], key);
}

__device__ __forceinline__ void ce_(unsigned &x, unsigned &y) {
    unsigned lo = umin_(x, y); y = umax_(x, y); x = lo;
}

// Bitonic merge network for a length-10 bitonic sequence (15 CEs).
__device__ __forceinline__ void bitonic10(unsigned a[TOPK]) {
    ce_(a[0], a[8]); ce_(a[1], a[9]);
    ce_(a[0], a[4]); ce_(a[1], a[5]); ce_(a[2], a[6]); ce_(a[3], a[7]);
    ce_(a[0], a[2]); ce_(a[1], a[3]); ce_(a[4], a[6]); ce_(a[5], a[7]);
    ce_(a[0], a[1]); ce_(a[2], a[3]); ce_(a[4], a[5]); ce_(a[6], a[7]); ce_(a[8], a[9]);
}

// Merge two sorted 10-lists: ours + partner lane's (halver + bitonic net).
__device__ __forceinline__ void merge_shfl(unsigned a[TOPK], int w) {
    unsigned b[TOPK];
#pragma unroll
    for (int k = 0; k < TOPK; ++k) b[k] = (unsigned)__shfl_xor((int)a[k], w, 64);
#pragma unroll
    for (int k = 0; k < TOPK; ++k) a[k] = umin_(a[k], b[TOPK - 1 - k]);
    bitonic10(a);
}

// Process two candidates with both loads issued before either use.
__device__ __forceinline__ void scan2(
    unsigned a[TOPK], const float4* __restrict__ sorted,
    unsigned p0, unsigned p1, unsigned s, float mx, float my, float mz)
{
    float4 c0 = sorted[p0];
    float4 c1 = sorted[p1];
    float dx0 = c0.x - mx, dy0 = c0.y - my, dz0 = c0.z - mz;
    float dx1 = c1.x - mx, dy1 = c1.y - my, dz1 = c1.z - mz;
    float d20 = fmaf(dx0, dx0, fmaf(dy0, dy0, dz0 * dz0));
    float d21 = fmaf(dx1, dx1, fmaf(dy1, dy1, dz1 * dz1));
    unsigned k0 = (__float_as_uint(d20) & 0xFFFFC000u) | p0;
    unsigned k1 = (__float_as_uint(d21) & 0xFFFFC000u) | p1;
    if (p0 == s) k0 = 0xFFFFFFFFu;
    if (p1 == s) k1 = 0xFFFFFFFFu;
    unsigned kmin = umin_(k0, k1), kmax = umax_(k0, k1);
    if (kmin < a[TOPK - 1]) {
        chain_insert(a, kmin);
        if (kmax < a[TOPK - 1]) chain_insert(a, kmax);
    }
}

__device__ __forceinline__ void scan1(
    unsigned a[TOPK], const float4* __restrict__ sorted,
    unsigned p, unsigned s, float mx, float my, float mz)
{
    float4 c = sorted[p];
    float dx = c.x - mx, dy = c.y - my, dz = c.z - mz;
    float d2 = fmaf(dx, dx, fmaf(dy, dy, dz * dz));
    unsigned key = (__float_as_uint(d2) & 0xFFFFC000u) | p;
    if (p == s) key = 0xFFFFFFFFu;
    if (key < a[TOPK - 1]) chain_insert(a, key);
}

__device__ __forceinline__ int cellf(float v) {
    int b = (int)((v - XMIN) * INVBW);
    return min(max(b, 0), NBX - 1);
}

// ---- fused trivial losses + 3-D cell histogram ----------------------------
__global__ __launch_bounds__(256) void setup_kernel(
    const float* __restrict__ pos, const float* __restrict__ opac,
    const float* __restrict__ scales, float* __restrict__ parts,
    unsigned* __restrict__ hist)
{
    int i = blockIdx.x * 256 + threadIdx.x;
    float o = opac[i];
    float d = o - 0.5f;
    float s_sp = fabsf(o);
    float s_op = d * d;
    float s_sc = fabsf(scales[3 * i] - 1.0f) + fabsf(scales[3 * i + 1] - 1.0f)
               + fabsf(scales[3 * i + 2] - 1.0f);
    int bx = cellf(pos[3 * i]);
    int by = cellf(pos[3 * i + 1]);
    int bz = cellf(pos[3 * i + 2]);
    atomicAdd(&hist[(bx << 10) | (by << 5) | bz], 1u);
#pragma unroll
    for (int off = 32; off > 0; off >>= 1) {
        s_sp += __shfl_down(s_sp, off, 64);
        s_sc += __shfl_down(s_sc, off, 64);
        s_op += __shfl_down(s_op, off, 64);
    }
    if ((threadIdx.x & 63) == 0) {
        const int row = (blockIdx.x * 4 + (threadIdx.x >> 6)) & (NSLOT - 1);
        atomicAdd(&parts[row * 32 + 0], s_sp);
        atomicAdd(&parts[row * 32 + 1], s_sc);
        atomicAdd(&parts[row * 32 + 2], s_op);
    }
}

// Exclusive scan over 32768 bins: shfl-based (2 barriers total).
// Also re-zeroes hist in place (it becomes the scatter cnt array).
__global__ __launch_bounds__(1024) void prefix_scan(
    unsigned* __restrict__ hist, unsigned* __restrict__ base)
{
    __shared__ unsigned wsum[16];
    const int t = threadIdx.x;
    const int lane = t & 63, wid = t >> 6;
    unsigned loc[32];
    uint4* h4 = (uint4*)(hist + t * 32);
#pragma unroll
    for (int j = 0; j < 8; ++j) {
        uint4 h = h4[j];
        loc[4 * j + 0] = h.x; loc[4 * j + 1] = h.y;
        loc[4 * j + 2] = h.z; loc[4 * j + 3] = h.w;
    }
    unsigned run = 0;
#pragma unroll
    for (int j = 0; j < 32; ++j) { unsigned v = loc[j]; loc[j] = run; run += v; }
    unsigned inc = run;
#pragma unroll
    for (int off = 1; off < 64; off <<= 1) {
        unsigned v = (unsigned)__shfl_up((int)inc, off, 64);
        if (lane >= off) inc += v;
    }
    if (lane == 63) wsum[wid] = inc;
    __syncthreads();
    if (wid == 0) {
        unsigned w = (lane < 16) ? wsum[lane] : 0u;
#pragma unroll
        for (int off = 1; off < 16; off <<= 1) {
            unsigned v = (unsigned)__shfl_up((int)w, off, 64);
            if (lane >= off) w += v;
        }
        if (lane < 16) wsum[lane] = w;
    }
    __syncthreads();
    const unsigned wbase = (wid > 0) ? wsum[wid - 1] : 0u;
    const unsigned tbase = wbase + inc - run;
    uint4* b4 = (uint4*)(base + t * 32);
#pragma unroll
    for (int j = 0; j < 8; ++j) {
        b4[j] = make_uint4(loc[4 * j] + tbase, loc[4 * j + 1] + tbase,
                           loc[4 * j + 2] + tbase, loc[4 * j + 3] + tbase);
        h4[j] = make_uint4(0u, 0u, 0u, 0u);
    }
    if (t == 1023) base[NBK] = NPTS;
}

__global__ __launch_bounds__(256) void scatter_sorted(
    const float* __restrict__ pos, const float* __restrict__ opac,
    const unsigned* __restrict__ base, unsigned* __restrict__ cnt,
    float4* __restrict__ sorted)
{
    int i = blockIdx.x * 256 + threadIdx.x;
    float x = pos[3 * i], y = pos[3 * i + 1], z = pos[3 * i + 2];
    int b = (cellf(x) << 10) | (cellf(y) << 5) | cellf(z);
    unsigned p = base[b] + atomicAdd(&cnt[b], 1u);
    sorted[p] = make_float4(x, y, z, opac[i]);
}

// ---- unified kNN: ONE WAVE per point --------------------------------------
// Phase A: top-10 bound of the +/-128 cell-order window (4 candidates/lane,
//   6-level merge) -> sentinel (strict upper bound on the true 10-NN key).
// Phase B: ALL column-pair bounds loaded lane-parallel into registers.
// Phase C: 8 GROUPS of 8 lanes; group g scans pairs j = g, g+8, ... with a
//   2-deep pipelined run walk -- 8 z-runs in flight instead of 1, killing
//   the serial-pair latency chain (the r9 straggler). Groups' candidate
//   sets are disjoint; the 6-level merge converges the wave as before.
__global__ __launch_bounds__(256) void knn_all(
    const float4* __restrict__ sorted, const unsigned* __restrict__ base,
    float* __restrict__ parts)
{
    const int lane = threadIdx.x & 63;
    const int s    = (blockIdx.x * 256 + threadIdx.x) >> 6;   // wave id = point

    const float4 me = sorted[s];

    // ---- phase A: bound ----
    unsigned a[TOPK];
#pragma unroll
    for (int k = 0; k < TOPK; ++k) a[k] = 0xFFFFFFFFu;
    {
        const int dir = lane >> 5;              // 0 right, 1 left
        const int start = 1 + (lane & 31) * 4;
#pragma unroll
        for (int t = 0; t < 4; ++t) {
            int p = dir ? (s - start - t) : (s + start + t);
            int pc = min(max(p, 0), NPTS - 1);
            float4 c = sorted[pc];
            float dx = c.x - me.x, dy = c.y - me.y, dz = c.z - me.z;
            float d2 = fmaf(dx, dx, fmaf(dy, dy, dz * dz));
            unsigned key = (__float_as_uint(d2) & 0xFFFFC000u) | (unsigned)pc;
            if (p < 0 || p >= NPTS) key = 0xFFFFFFFFu;
            chain_insert(a, key);
        }
    }
    merge_shfl(a, 1);  merge_shfl(a, 2);  merge_shfl(a, 4);
    merge_shfl(a, 8);  merge_shfl(a, 16); merge_shfl(a, 32);
    const unsigned sentinel = (a[TOPK - 1] & 0xFFFFC000u) + SENT_STEP;
    const float R = sqrtf(__uint_as_float(sentinel)) + 1e-6f;

    const int bxlo = cellf(me.x - R), bxhi = cellf(me.x + R);
    const int bylo = cellf(me.y - R), byhi = cellf(me.y + R);
    const int bzlo = cellf(me.z - R), bzhi = cellf(me.z + R);
    const int nyw   = byhi - bylo + 1;
    const int npair = (bxhi - bxlo + 1) * nyw;

    // ---- phase B/C: lane-parallel bounds + group-parallel pair scan ----
#pragma unroll
    for (int k = 0; k < TOPK; ++k) a[k] = sentinel;

    const int grp = lane >> 3;                  // group 0..7
    const int gl  = lane & 7;                   // lane in group

    for (int cbase = 0; cbase < npair; cbase += 64) {
        const int cnum = min(64, npair - cbase);
        unsigned mylo = 0, myhi = 0;
        const int pi = cbase + lane;
        if (pi < npair) {
            const int qx = pi / nyw;
            const int cb = ((bxlo + qx) << 10) | ((bylo + pi - qx * nyw) << 5);
            mylo = base[cb + bzlo];
            myhi = base[cb + bzhi + 1];
        }
        for (int j = grp; j < cnum; j += 8) {
            const unsigned lo = (unsigned)__shfl((int)mylo, j, 64);
            const unsigned hi = (unsigned)__shfl((int)myhi, j, 64);
            unsigned p = lo + gl;
            for (; p + 8 < hi; p += 16)
                scan2(a, sorted, p, p + 8, (unsigned)s, me.x, me.y, me.z);
            if (p < hi)
                scan1(a, sorted, p, (unsigned)s, me.x, me.y, me.z);
        }
    }

    merge_shfl(a, 1);  merge_shfl(a, 2);  merge_shfl(a, 4);
    merge_shfl(a, 8);  merge_shfl(a, 16); merge_shfl(a, 32);

    float v = 0.0f;
    if (lane < TOPK) {
        int j = (int)(a[lane] & 0x3FFFu);
        v = fabsf(me.w - sorted[j].w);
    }
    v += __shfl_down(v, 8, 64);
    v += __shfl_down(v, 4, 64);
    v += __shfl_down(v, 2, 64);
    v += __shfl_down(v, 1, 64);
    if (lane == 0)
        atomicAdd(&parts[(s & (NSLOT - 1)) * 32 + 3], v);
}

// ---- combine --------------------------------------------------------------
__global__ void combine(const float* __restrict__ parts, float* __restrict__ out)
{
    const int lane = threadIdx.x;                // 64 threads
    float sp = 0.0f, sc = 0.0f, op = 0.0f, sm = 0.0f;
#pragma unroll
    for (int r = 0; r < NSLOT / 64; ++r) {
        float4 p = *(const float4*)(parts + (r * 64 + lane) * 32);
        sp += p.x; sc += p.y; op += p.z; sm += p.w;
    }
#pragma unroll
    for (int off = 32; off > 0; off >>= 1) {
        sp += __shfl_down(sp, off, 64);
        sc += __shfl_down(sc, off, 64);
        op += __shfl_down(op, off, 64);
        sm += __shfl_down(sm, off, 64);
    }
    if (lane == 0) {
        const float n = (float)NPTS;
        out[0] = 0.01f * (sp / n) + 0.1f * (sm / (n * 10.0f))
               + sc / (3.0f * n) + op / n;
    }
}

extern "C" void kernel_launch(void* const* d_in, const int* in_sizes, int n_in,
                              void* d_out, int out_size, void* d_ws, size_t ws_size,
                              hipStream_t stream)
{
    const float* pos    = (const float*)d_in[0];
    const float* opac   = (const float*)d_in[1];
    const float* scales = (const float*)d_in[2];
    float* out = (float*)d_out;

    char* ws = (char*)d_ws;
    float*    parts  = (float*)(ws + 128);
    unsigned* histcnt= (unsigned*)(ws + 33024);    // hist -> cnt
    unsigned* base   = (unsigned*)(ws + 164096);
    float4*   sorted = (float4*)(ws + 295296);

    hipMemsetAsync(ws, 0, 164096, stream);

    setup_kernel  <<<NPTS / 256, 256, 0, stream>>>(pos, opac, scales, parts, histcnt);
    prefix_scan   <<<1, 1024, 0, stream>>>(histcnt, base);
    scatter_sorted<<<NPTS / 256, 256, 0, stream>>>(pos, opac, base, histcnt, sorted);
    knn_all       <<<NPTS / 4, 256, 0, stream>>>(sorted, base, parts);
    combine       <<<1, 64, 0, stream>>>(parts, out);
}